// Round 2
// baseline (287.223 us; speedup 1.0000x reference)
//
#include <hip/hip_runtime.h>
#include <math.h>

// Problem constants
#define NB 16      // batch
#define NE 128     // experts / channels
#define NK 8
#define HW 16384   // 128*128
#define NPIX (NB * HW)

// f32 transposed gate weights: gwT[e][f] = gate_w[f][e]
__device__ float g_gwT[NE * NE];

__global__ __launch_bounds__(256) void cvt_gw_kernel(const float* __restrict__ gate_w) {
    int i = blockIdx.x * 256 + threadIdx.x;   // i = e*128 + f
    if (i < NE * NE) {
        int e = i >> 7;
        int f = i & 127;
        g_gwT[i] = gate_w[f * NE + e];
    }
}

__global__ __launch_bounds__(256) void moe_kernel(const float* __restrict__ experts,
                                                  const float* __restrict__ gate_b,
                                                  float* __restrict__ out) {
    const int p  = blockIdx.x * 256 + threadIdx.x;   // pixel id
    const int n  = p >> 14;                          // /16384
    const int hw = p & (HW - 1);

    const float* xp = experts + ((size_t)n * NE * HW + hw);   // channel stride HW

    // ---- logits: f32 ascending-e FMA chain (mirrors BLAS/np-einsum accumulation) ----
    float acc[NE];
#pragma unroll
    for (int f = 0; f < NE; ++f) acc[f] = 0.0f;

    for (int e = 0; e < NE; ++e) {
        float xe = xp[(size_t)e * HW];
        const float* gw = &g_gwT[e * NE];   // wave-uniform scalar loads
#pragma unroll
        for (int f = 0; f < NE; ++f) {
            acc[f] = fmaf(gw[f], xe, acc[f]);
        }
    }

    // + bias (zeros in this problem; mirrored for fidelity)
#pragma unroll
    for (int f = 0; f < NE; ++f) acc[f] = acc[f] + gate_b[f];

    // ---- softmax, mirroring f32 numpy semantics ----
    float m = acc[0];
#pragma unroll
    for (int f = 1; f < NE; ++f) m = fmaxf(m, acc[f]);

    // correctly-rounded f32 exp of (l - m)
#pragma unroll
    for (int f = 0; f < NE; ++f) {
        acc[f] = (float)exp((double)(acc[f] - m));
    }

    // denominator: sequential ascending f32 sum (np strided-axis reduce order)
    float s = acc[0];
#pragma unroll
    for (int f = 1; f < NE; ++f) s = s + acc[f];

    // routing weights: IEEE f32 divide (ties happen in weight space -> must mirror)
#pragma unroll
    for (int f = 0; f < NE; ++f) acc[f] = acc[f] / s;

    // ---- top-8 on (w desc, idx asc): stable, ties -> lower index ----
    float t_v[NK];
    int   t_i[NK];
#pragma unroll
    for (int i = 0; i < NK; ++i) { t_v[i] = -1.0f; t_i[i] = 0; }

#pragma unroll
    for (int f = 0; f < NE; ++f) {
        float v  = acc[f];
        int   ix = f;
#pragma unroll
        for (int i = 0; i < NK; ++i) {
            bool gt = v > t_v[i];
            float tv = t_v[i]; int ti = t_i[i];
            t_v[i] = gt ? v  : tv;
            t_i[i] = gt ? ix : ti;
            v      = gt ? tv : v;
            ix     = gt ? ti : ix;
        }
    }

    // ---- gather + scale + write ----
    float* op = out + ((size_t)n * NK * HW + hw);
#pragma unroll
    for (int k = 0; k < NK; ++k) {
        float xv = xp[(size_t)t_i[k] * HW];
        op[(size_t)k * HW] = t_v[k] * xv;
    }
}

extern "C" void kernel_launch(void* const* d_in, const int* in_sizes, int n_in,
                              void* d_out, int out_size, void* d_ws, size_t ws_size,
                              hipStream_t stream) {
    // inputs: 0=x (unused), 1=experts [N,E,H,W] f32, 2=gate_w [E,E] f32, 3=gate_b [E] f32
    const float* experts = (const float*)d_in[1];
    const float* gate_w  = (const float*)d_in[2];
    const float* gate_b  = (const float*)d_in[3];
    float* out = (float*)d_out;

    hipLaunchKernelGGL(cvt_gw_kernel, dim3((NE * NE + 255) / 256), dim3(256), 0, stream, gate_w);
    hipLaunchKernelGGL(moe_kernel, dim3(NPIX / 256), dim3(256), 0, stream, experts, gate_b, out);
}